// Round 2
// baseline (42670.636 us; speedup 1.0000x reference)
//
#include <hip/hip_runtime.h>

#define NP   19
#define EPB  16
#define BLK  256

namespace {
constexpr int P_IO[NP]  = {0,0,0, 1,1,1,1,1,1,1, 2,2,2,2, 2,2,2,2,2};
constexpr int P_II[NP]  = {0,1,2, 0,1,1,1,2,2,2, 0,1,1,1, 2,2,2,2,2};
constexpr int P_LF[NP]  = {0,1,2, 1,0,1,2,1,2,3, 2,1,2,3, 0,1,2,3,4};
constexpr int P_CGB[NP] = {0,1,10, 35,44,53,80,125,170,245, 350,375,420,495, 600,625,700,825,1000};
constexpr float NORMLF[5] = {1.0f, 0.57735026918962576f, 0.44721359549995794f,
                             0.37796447300922722f, 0.33333333333333333f};
}

// ---- per-path body, everything compile-time except lane data ----
template<int P>
__device__ __forceinline__ void process_path(
    const int l, const int eloc,
    const float fA, const float (&fB)[3], const float (&fC)[5],
    const float (&rr)[10], const float (&y)[25], float (&acc)[9],
    const float* __restrict__ R,
    const float* __restrict__ s_cg,
    float (*__restrict__ s_cgy)[25],
    float (*__restrict__ s_tmp)[84])
{
    constexpr int io = P_IO[P], ii = P_II[P], lf = P_LF[P];
    constexpr int dO = 2*io + 1, dI = 2*ii + 1, dF = 2*lf + 1;
    constexpr int nOI = dO * dI;
    constexpr int yb  = lf * lf;
    constexpr float nrm = NORMLF[lf];

    // --- cgY[o,i] = norm * sum_f cg[o,i,f] * Y[f]  (lanes cover flat (o,i)) ---
#pragma unroll
    for (int j0 = 0; j0 < nOI; j0 += 16) {
        const int j = j0 + l;
        if (j < nOI) {
            float s = 0.f;
#pragma unroll
            for (int f = 0; f < dF; ++f)
                s += s_cg[P_CGB[P] + j*dF + f] * y[yb + f];
            s_cgy[eloc][j] = s * nrm;
        }
    }
    __syncthreads();   // cgY visible to all lanes (prevents compiler load-PRE over the predicated store)

    // --- tmp[v,o] = sum_i F[v,i] * cgY[o,i]   (lane = v) ---
#pragma unroll
    for (int o = 0; o < dO; ++o) {
        float t = 0.f;
#pragma unroll
        for (int i = 0; i < dI; ++i) {
            float fv;
            if constexpr (ii == 0)      fv = fA;
            else if constexpr (ii == 1) fv = fB[i];
            else                        fv = fC[i];
            t += fv * s_cgy[eloc][o*dI + i];
        }
        s_tmp[eloc][o*16 + l] = t;
    }

    // --- W row: W[w, v] = sum_r radii[r] * R[r, P*256 + w*16 + v]  (lane = w) ---
    // (no LDS dependence — compiler free to schedule these loads early)
    float W[16];
#pragma unroll
    for (int v = 0; v < 16; ++v) W[v] = 0.f;
    const float* Rp = R + P*256 + l*16;
#pragma unroll
    for (int r = 0; r < 10; ++r) {
        const float4* q = reinterpret_cast<const float4*>(Rp + r*4864);
        const float4 q0 = q[0], q1 = q[1], q2 = q[2], q3 = q[3];
        const float rv = rr[r];
        W[0]  += rv*q0.x; W[1]  += rv*q0.y; W[2]  += rv*q0.z; W[3]  += rv*q0.w;
        W[4]  += rv*q1.x; W[5]  += rv*q1.y; W[6]  += rv*q1.z; W[7]  += rv*q1.w;
        W[8]  += rv*q2.x; W[9]  += rv*q2.y; W[10] += rv*q2.z; W[11] += rv*q2.w;
        W[12] += rv*q3.x; W[13] += rv*q3.y; W[14] += rv*q3.z; W[15] += rv*q3.w;
    }

    __syncthreads();   // tmp visible to all lanes

    // --- out[w,o] += sum_v W[v] * tmp[v,o]   (lane = w) ---
#pragma unroll
    for (int o = 0; o < dO; ++o) {
        const float4* tq = reinterpret_cast<const float4*>(&s_tmp[eloc][o*16]);
        const float4 t0 = tq[0], t1 = tq[1], t2 = tq[2], t3 = tq[3];
        float s = W[0]*t0.x + W[1]*t0.y + W[2]*t0.z + W[3]*t0.w
                + W[4]*t1.x + W[5]*t1.y + W[6]*t1.z + W[7]*t1.w
                + W[8]*t2.x + W[9]*t2.y + W[10]*t2.z + W[11]*t2.w
                + W[12]*t3.x + W[13]*t3.y + W[14]*t3.z + W[15]*t3.w;
        acc[io*io + o] += s;
    }
}

template<int P>
__device__ __forceinline__ void process_all(
    const int l, const int eloc,
    const float fA, const float (&fB)[3], const float (&fC)[5],
    const float (&rr)[10], const float (&y)[25], float (&acc)[9],
    const float* __restrict__ R, const float* __restrict__ s_cg,
    float (*__restrict__ s_cgy)[25], float (*__restrict__ s_tmp)[84])
{
    if constexpr (P < NP) {
        process_path<P>(l, eloc, fA, fB, fC, rr, y, acc, R, s_cg, s_cgy, s_tmp);
        process_all<P+1>(l, eloc, fA, fB, fC, rr, y, acc, R, s_cg, s_cgy, s_tmp);
    }
}

__global__ __launch_bounds__(BLK)
void se3_conv(const float* __restrict__ F, const float* __restrict__ R,
              const float* __restrict__ Ys, const float* __restrict__ Rad,
              const float* __restrict__ cg, const float* __restrict__ Nn,
              const int* __restrict__ Ma, const int* __restrict__ Mb,
              float* __restrict__ Out, const int nE)
{
    __shared__ float s_cg[1225];
    __shared__ float s_cgy[EPB][25];
    __shared__ float s_tmp[EPB][84];   // 5*16 + 4 pad: keeps 16B align, breaks group bank clash

    const int tid = threadIdx.x;
    for (int j = tid; j < 1225; j += BLK) s_cg[j] = cg[j];
    __syncthreads();

    const int l    = tid & 15;
    const int eloc = tid >> 4;
    const int e    = blockIdx.x * EPB + eloc;
    const bool active = (e < nE);           // nE % 16 == 0 in practice; keep robust
    const int  esafe  = active ? e : 0;     // no early return: barriers below need all threads

    const int a = Ma[esafe];
    const int b = Mb[esafe];

    const float* Fb = F + b * 144;
    const float fA = Fb[l];
    float fB[3], fC[5];
#pragma unroll
    for (int i = 0; i < 3; ++i) fB[i] = Fb[16 + l*3 + i];
#pragma unroll
    for (int i = 0; i < 5; ++i) fC[i] = Fb[64 + l*5 + i];

    float rr[10];
    const float* rad = Rad + esafe * 10;
#pragma unroll
    for (int r = 0; r < 10; ++r) rr[r] = rad[r];

    float y[25];
    const float* yrow = Ys + esafe * 25;
#pragma unroll
    for (int k = 0; k < 25; ++k) y[k] = yrow[k];

    float acc[9];
#pragma unroll
    for (int k = 0; k < 9; ++k) acc[k] = 0.f;

    process_all<0>(l, eloc, fA, fB, fC, rr, y, acc, R, s_cg, s_cgy, s_tmp);

    if (active) {
        // scatter: scale message by n_norm[dest] (== scaling the segment sum)
        const float nn = Nn[a];
        float* orow = Out + a * 144;
        atomicAdd(&orow[l], acc[0] * nn);
#pragma unroll
        for (int o = 0; o < 3; ++o) atomicAdd(&orow[16 + l*3 + o], acc[1+o] * nn);
#pragma unroll
        for (int o = 0; o < 5; ++o) atomicAdd(&orow[64 + l*5 + o], acc[4+o] * nn);
    }
}

extern "C" void kernel_launch(void* const* d_in, const int* in_sizes, int n_in,
                              void* d_out, int out_size, void* d_ws, size_t ws_size,
                              hipStream_t stream) {
    const float* F   = (const float*)d_in[0];
    const float* R   = (const float*)d_in[1];
    const float* Ys  = (const float*)d_in[2];
    const float* Rad = (const float*)d_in[3];
    const float* cg  = (const float*)d_in[4];
    const float* Nn  = (const float*)d_in[5];
    const int*   Ma  = (const int*)d_in[6];
    const int*   Mb  = (const int*)d_in[7];
    float* Out = (float*)d_out;

    const int nE = in_sizes[6];   // map_ab_p_to_a element count
    hipMemsetAsync(Out, 0, (size_t)out_size * sizeof(float), stream);

    const int grid = (nE + EPB - 1) / EPB;
    hipLaunchKernelGGL(se3_conv, dim3(grid), dim3(BLK), 0, stream,
                       F, R, Ys, Rad, cg, Nn, Ma, Mb, Out, nE);
}

// Round 3
// 9027.569 us; speedup vs baseline: 4.7267x; 4.7267x over previous
//
#include <hip/hip_runtime.h>

#define NP   19
#define EPB  16
#define BLK  256
#define WST  260   // s_W row stride in words: 256+4 so row starts spread across banks

namespace {
constexpr int P_IO[NP]  = {0,0,0, 1,1,1,1,1,1,1, 2,2,2,2, 2,2,2,2,2};
constexpr int P_II[NP]  = {0,1,2, 0,1,1,1,2,2,2, 0,1,1,1, 2,2,2,2,2};
constexpr int P_LF[NP]  = {0,1,2, 1,0,1,2,1,2,3, 2,1,2,3, 0,1,2,3,4};
constexpr int P_CGB[NP] = {0,1,10, 35,44,53,80,125,170,245, 350,375,420,495, 600,625,700,825,1000};
constexpr float NORMLF[5] = {1.0f, 0.57735026918962576f, 0.44721359549995794f,
                             0.37796447300922722f, 0.33333333333333333f};
}

template<int P>
__device__ __forceinline__ void process_path(
    const int l, const int eloc, const int lane, const int wv,
    const float fA, const float (&fB)[3], const float (&fC)[5],
    const float (&rsh)[4][10], const float (&y)[25], float (&acc)[9],
    const float* __restrict__ R, const float* __restrict__ s_cg,
    float (*__restrict__ s_cgy)[25], float (*__restrict__ s_tmp)[84],
    float* __restrict__ s_W)
{
    constexpr int io = P_IO[P], ii = P_II[P], lf = P_LF[P];
    constexpr int dO = 2*io+1, dI = 2*ii+1, dF = 2*lf+1;
    constexpr int nOI = dO*dI, yb = lf*lf;
    constexpr float nrm = NORMLF[lf];
    constexpr int buf = (P & 1) * (EPB * WST);

    // --- cooperative W tile: this wave computes W[its 4 edges][256 cols].
    // lane covers columns 4*lane..4*lane+3; W[e][w*16+v] = sum_r rad[e][r]*R[r][P*256+w*16+v]
    float4 Rq[10];
    const float* Rbase = R + P*256 + 4*lane;
#pragma unroll
    for (int r = 0; r < 10; ++r)
        Rq[r] = *reinterpret_cast<const float4*>(Rbase + r*4864);
#pragma unroll
    for (int e4 = 0; e4 < 4; ++e4) {
        float wx = 0.f, wy = 0.f, wz = 0.f, ww = 0.f;
#pragma unroll
        for (int r = 0; r < 10; ++r) {
            const float rv = rsh[e4][r];
            wx += rv*Rq[r].x; wy += rv*Rq[r].y; wz += rv*Rq[r].z; ww += rv*Rq[r].w;
        }
        float4 w4; w4.x = wx; w4.y = wy; w4.z = wz; w4.w = ww;
        *reinterpret_cast<float4*>(&s_W[buf + (wv*4 + e4)*WST + 4*lane]) = w4;
    }

    // --- cgY[o,i] = norm * sum_f cg[o,i,f] * Y[f]  (lanes cover flat (o,i)) ---
#pragma unroll
    for (int j0 = 0; j0 < nOI; j0 += 16) {
        const int j = j0 + l;
        if (j < nOI) {
            float s = 0.f;
#pragma unroll
            for (int f = 0; f < dF; ++f)
                s += s_cg[P_CGB[P] + j*dF + f] * y[yb + f];
            s_cgy[eloc][j] = s * nrm;
        }
    }
    __syncthreads();   // cgY (and nothing else) must be visible before tmp stage

    // --- tmp[v,o] = sum_i F[v,i] * cgY[o,i]   (lane = v) ---
#pragma unroll
    for (int o = 0; o < dO; ++o) {
        float t = 0.f;
#pragma unroll
        for (int i = 0; i < dI; ++i) {
            float fv;
            if constexpr (ii == 0)      fv = fA;
            else if constexpr (ii == 1) fv = fB[i];
            else                        fv = fC[i];
            t += fv * s_cgy[eloc][o*dI + i];
        }
        s_tmp[eloc][o*16 + l] = t;
    }
    __syncthreads();   // tmp + W visible

    // --- out[w,o] += sum_v W[w,v] * tmp[v,o]   (lane = w) ---
    const float* Wrow = &s_W[buf + eloc*WST + 16*l];
    const float4 w0 = *reinterpret_cast<const float4*>(Wrow);
    const float4 w1 = *reinterpret_cast<const float4*>(Wrow + 4);
    const float4 w2 = *reinterpret_cast<const float4*>(Wrow + 8);
    const float4 w3 = *reinterpret_cast<const float4*>(Wrow + 12);
#pragma unroll
    for (int o = 0; o < dO; ++o) {
        const float4* tq = reinterpret_cast<const float4*>(&s_tmp[eloc][o*16]);
        const float4 t0 = tq[0], t1 = tq[1], t2 = tq[2], t3 = tq[3];
        float s = w0.x*t0.x + w0.y*t0.y + w0.z*t0.z + w0.w*t0.w
                + w1.x*t1.x + w1.y*t1.y + w1.z*t1.z + w1.w*t1.w
                + w2.x*t2.x + w2.y*t2.y + w2.z*t2.z + w2.w*t2.w
                + w3.x*t3.x + w3.y*t3.y + w3.z*t3.z + w3.w*t3.w;
        acc[io*io + o] += s;
    }
}

template<int P>
__device__ __forceinline__ void process_all(
    const int l, const int eloc, const int lane, const int wv,
    const float fA, const float (&fB)[3], const float (&fC)[5],
    const float (&rsh)[4][10], const float (&y)[25], float (&acc)[9],
    const float* __restrict__ R, const float* __restrict__ s_cg,
    float (*__restrict__ s_cgy)[25], float (*__restrict__ s_tmp)[84],
    float* __restrict__ s_W)
{
    if constexpr (P < NP) {
        process_path<P>(l, eloc, lane, wv, fA, fB, fC, rsh, y, acc, R, s_cg, s_cgy, s_tmp, s_W);
        process_all<P+1>(l, eloc, lane, wv, fA, fB, fC, rsh, y, acc, R, s_cg, s_cgy, s_tmp, s_W);
    }
}

__global__ __launch_bounds__(BLK, 3)
void se3_conv(const float* __restrict__ F, const float* __restrict__ R,
              const float* __restrict__ Ys, const float* __restrict__ Rad,
              const float* __restrict__ cg, const float* __restrict__ Nn,
              const int* __restrict__ Ma, const int* __restrict__ Mb,
              float* __restrict__ Out, const int nE)
{
    __shared__ float s_cg[1225];
    __shared__ float s_cgy[EPB][25];
    __shared__ float s_tmp[EPB][84];
    __shared__ float s_W[2 * EPB * WST];   // double-buffered W tiles

    const int tid = threadIdx.x;
    for (int j = tid; j < 1225; j += BLK) s_cg[j] = cg[j];

    const int l    = tid & 15;
    const int eloc = tid >> 4;
    const int lane = tid & 63;
    const int wv   = tid >> 6;
    const int e    = blockIdx.x * EPB + eloc;
    const bool active = (e < nE);
    const int  esafe  = active ? e : 0;

    const int a = Ma[esafe];
    const int b = Mb[esafe];

    const float* Fb = F + b * 144;
    const float fA = Fb[l];
    float fB[3], fC[5];
#pragma unroll
    for (int i = 0; i < 3; ++i) fB[i] = Fb[16 + l*3 + i];
#pragma unroll
    for (int i = 0; i < 5; ++i) fC[i] = Fb[64 + l*5 + i];

    // own-edge radii, then broadcast so every lane holds its wave's 4 edges' radii
    float rr[10];
    const float* rad = Rad + esafe * 10;
#pragma unroll
    for (int r = 0; r < 10; ++r) rr[r] = rad[r];
    float rsh[4][10];
#pragma unroll
    for (int e4 = 0; e4 < 4; ++e4)
#pragma unroll
        for (int r = 0; r < 10; ++r)
            rsh[e4][r] = __shfl(rr[r], e4 * 16);   // src lane within the 64-wide wave

    float y[25];
    const float* yrow = Ys + esafe * 25;
#pragma unroll
    for (int k = 0; k < 25; ++k) y[k] = yrow[k];

    float acc[9];
#pragma unroll
    for (int k = 0; k < 9; ++k) acc[k] = 0.f;

    __syncthreads();   // s_cg staged

    process_all<0>(l, eloc, lane, wv, fA, fB, fC, rsh, y, acc, R, s_cg, s_cgy, s_tmp, &s_W[0]);

    if (active) {
        const float nn = Nn[a];
        float* orow = Out + a * 144;
        unsafeAtomicAdd(&orow[l], acc[0] * nn);
#pragma unroll
        for (int o = 0; o < 3; ++o) unsafeAtomicAdd(&orow[16 + l*3 + o], acc[1+o] * nn);
#pragma unroll
        for (int o = 0; o < 5; ++o) unsafeAtomicAdd(&orow[64 + l*5 + o], acc[4+o] * nn);
    }
}

extern "C" void kernel_launch(void* const* d_in, const int* in_sizes, int n_in,
                              void* d_out, int out_size, void* d_ws, size_t ws_size,
                              hipStream_t stream) {
    const float* F   = (const float*)d_in[0];
    const float* R   = (const float*)d_in[1];
    const float* Ys  = (const float*)d_in[2];
    const float* Rad = (const float*)d_in[3];
    const float* cg  = (const float*)d_in[4];
    const float* Nn  = (const float*)d_in[5];
    const int*   Ma  = (const int*)d_in[6];
    const int*   Mb  = (const int*)d_in[7];
    float* Out = (float*)d_out;

    const int nE = in_sizes[6];
    hipMemsetAsync(Out, 0, (size_t)out_size * sizeof(float), stream);

    const int grid = (nE + EPB - 1) / EPB;
    hipLaunchKernelGGL(se3_conv, dim3(grid), dim3(BLK), 0, stream,
                       F, R, Ys, Rad, cg, Nn, Ma, Mb, Out, nE);
}

// Round 4
// 8053.194 us; speedup vs baseline: 5.2986x; 1.1210x over previous
//
#include <hip/hip_runtime.h>

#define NP   19
#define EPB  16
#define BLK  256
#define WST  260        // s_W row stride (words): mult of 4 (float4 reads) + pad
#define RSTRIDE 4864    // P_TOTAL = 19*256 columns in R

namespace {
constexpr int P_IO[NP]  = {0,0,0, 1,1,1,1,1,1,1, 2,2,2,2, 2,2,2,2,2};
constexpr int P_II[NP]  = {0,1,2, 0,1,1,1,2,2,2, 0,1,1,1, 2,2,2,2,2};
constexpr int P_LF[NP]  = {0,1,2, 1,0,1,2,1,2,3, 2,1,2,3, 0,1,2,3,4};
constexpr int P_CGB[NP] = {0,1,10, 35,44,53,80,125,170,245, 350,375,420,495, 600,625,700,825,1000};
constexpr float NORMLF[5] = {1.0f, 0.57735026918962576f, 0.44721359549995794f,
                             0.37796447300922722f, 0.33333333333333333f};
}

template<int P>
__device__ __forceinline__ void process_path(
    const int tid, const int l, const int eloc,
    const float fA, const float (&fB)[3], const float (&fC)[5],
    const float (&y)[25], float (&acc)[9],
    const float* __restrict__ R, const float* __restrict__ s_cg,
    const float (*__restrict__ s_rad)[10],
    float (*__restrict__ s_cgy)[25], float (*__restrict__ s_tmp)[84],
    float* __restrict__ s_W)
{
    constexpr int io = P_IO[P], ii = P_II[P], lf = P_LF[P];
    constexpr int dO = 2*io+1, dI = 2*ii+1, dF = 2*lf+1;
    constexpr int nOI = dO*dI, yb = lf*lf;
    constexpr float nrm = NORMLF[lf];
    constexpr int buf = (P & 1) * (EPB * WST);

    // ---- stage 1a: cooperative W tile. thread tid owns column c=tid of 256.
    // W[e][c] = sum_r rad[e][r] * R[r][P*256 + c]; R loads coalesced across threads.
    {
        float rcol[10];
        const float* Rp = R + P*256 + tid;
#pragma unroll
        for (int r = 0; r < 10; ++r) rcol[r] = Rp[r * RSTRIDE];
#pragma unroll
        for (int e = 0; e < EPB; ++e) {
            float s = 0.f;
#pragma unroll
            for (int r = 0; r < 10; ++r) s += s_rad[e][r] * rcol[r];   // s_rad broadcast
            s_W[buf + e*WST + tid] = s;
        }
    }

    // ---- stage 1b: cgY[o,i] = norm * sum_f cg[o,i,f] * Y[f]  (16 lanes cover flat (o,i))
#pragma unroll
    for (int j0 = 0; j0 < nOI; j0 += 16) {
        const int j = j0 + l;
        if (j < nOI) {
            float s = 0.f;
#pragma unroll
            for (int f = 0; f < dF; ++f)
                s += s_cg[P_CGB[P] + j*dF + f] * y[yb + f];
            s_cgy[eloc][j] = s * nrm;
        }
    }
    __syncthreads();   // cgY + W(this buf) visible; prev-path tmp reads already done

    // ---- stage 2: tmp[v,o] = sum_i F[v,i] * cgY[o,i]   (lane = v)
#pragma unroll
    for (int o = 0; o < dO; ++o) {
        float t = 0.f;
#pragma unroll
        for (int i = 0; i < dI; ++i) {
            float fv;
            if constexpr (ii == 0)      fv = fA;
            else if constexpr (ii == 1) fv = fB[i];
            else                        fv = fC[i];
            t += fv * s_cgy[eloc][o*dI + i];
        }
        s_tmp[eloc][o*16 + l] = t;
    }
    __syncthreads();   // tmp visible

    // ---- stage 3: out[w,o] += sum_v W[w,v] * tmp[v,o]   (lane = w)
    const float* Wrow = &s_W[buf + eloc*WST + 16*l];
    const float4 w0 = *reinterpret_cast<const float4*>(Wrow);
    const float4 w1 = *reinterpret_cast<const float4*>(Wrow + 4);
    const float4 w2 = *reinterpret_cast<const float4*>(Wrow + 8);
    const float4 w3 = *reinterpret_cast<const float4*>(Wrow + 12);
#pragma unroll
    for (int o = 0; o < dO; ++o) {
        const float4* tq = reinterpret_cast<const float4*>(&s_tmp[eloc][o*16]);
        const float4 t0 = tq[0], t1 = tq[1], t2 = tq[2], t3 = tq[3];
        float s = w0.x*t0.x + w0.y*t0.y + w0.z*t0.z + w0.w*t0.w
                + w1.x*t1.x + w1.y*t1.y + w1.z*t1.z + w1.w*t1.w
                + w2.x*t2.x + w2.y*t2.y + w2.z*t2.z + w2.w*t2.w
                + w3.x*t3.x + w3.y*t3.y + w3.z*t3.z + w3.w*t3.w;
        acc[io*io + o] += s;
    }
}

template<int P>
__device__ __forceinline__ void process_all(
    const int tid, const int l, const int eloc,
    const float fA, const float (&fB)[3], const float (&fC)[5],
    const float (&y)[25], float (&acc)[9],
    const float* __restrict__ R, const float* __restrict__ s_cg,
    const float (*__restrict__ s_rad)[10],
    float (*__restrict__ s_cgy)[25], float (*__restrict__ s_tmp)[84],
    float* __restrict__ s_W)
{
    if constexpr (P < NP) {
        process_path<P>(tid, l, eloc, fA, fB, fC, y, acc, R, s_cg, s_rad, s_cgy, s_tmp, s_W);
        process_all<P+1>(tid, l, eloc, fA, fB, fC, y, acc, R, s_cg, s_rad, s_cgy, s_tmp, s_W);
    }
}

__global__ __launch_bounds__(BLK, 3)
void se3_conv(const float* __restrict__ F, const float* __restrict__ R,
              const float* __restrict__ Ys, const float* __restrict__ Rad,
              const float* __restrict__ cg, const float* __restrict__ Nn,
              const int* __restrict__ Ma, const int* __restrict__ Mb,
              float* __restrict__ Out, const int nE)
{
    __shared__ float s_cg[1225];
    __shared__ float s_rad[EPB][10];
    __shared__ float s_cgy[EPB][25];
    __shared__ float s_tmp[EPB][84];
    __shared__ float s_W[2 * EPB * WST];   // double-buffered W; epilogue aliases s_x here

    const int tid = threadIdx.x;
    for (int j = tid; j < 1225; j += BLK) s_cg[j] = cg[j];

    const int l    = tid & 15;
    const int eloc = tid >> 4;
    const int e    = blockIdx.x * EPB + eloc;
    const bool active = (e < nE);
    const int  esafe  = active ? e : 0;

    // stage radii for all EPB edges (one value per thread for tid<160)
    if (tid < EPB * 10) {
        const int se = tid / 10, sr = tid - se * 10;
        const int ge = blockIdx.x * EPB + se;
        s_rad[se][sr] = (ge < nE) ? Rad[ge * 10 + sr] : 0.f;
    }

    const int a = Ma[esafe];
    const int b = Mb[esafe];

    const float* Fb = F + b * 144;
    const float fA = Fb[l];
    float fB[3], fC[5];
#pragma unroll
    for (int i = 0; i < 3; ++i) fB[i] = Fb[16 + l*3 + i];
#pragma unroll
    for (int i = 0; i < 5; ++i) fC[i] = Fb[64 + l*5 + i];

    float y[25];
    const float* yrow = Ys + esafe * 25;
#pragma unroll
    for (int k = 0; k < 25; ++k) y[k] = yrow[k];

    float acc[9];
#pragma unroll
    for (int k = 0; k < 9; ++k) acc[k] = 0.f;

    __syncthreads();   // s_cg + s_rad staged

    process_all<0>(tid, l, eloc, fA, fB, fC, y, acc, R, s_cg, s_rad, s_cgy, s_tmp, &s_W[0]);

    // ---- epilogue: transpose messages through LDS so atomics are lane-contiguous ----
    __syncthreads();                 // all s_W reads done; safe to alias
    float* s_x = &s_W[0];            // s_x[eloc][144]
    const float nn = Nn[a];          // per-edge broadcast load
    {
        float* xr = &s_x[eloc * 144];
        xr[l] = acc[0] * nn;
#pragma unroll
        for (int o = 0; o < 3; ++o) xr[16 + l*3 + o] = acc[1+o] * nn;
#pragma unroll
        for (int o = 0; o < 5; ++o) xr[64 + l*5 + o] = acc[4+o] * nn;
    }
    __syncthreads();
    if (active) {
        float* orow = Out + a * 144;
        const float* xr = &s_x[eloc * 144];
#pragma unroll
        for (int j = 0; j < 9; ++j)
            unsafeAtomicAdd(&orow[j*16 + l], xr[j*16 + l]);   // 16 lanes contiguous per instr
    }
}

extern "C" void kernel_launch(void* const* d_in, const int* in_sizes, int n_in,
                              void* d_out, int out_size, void* d_ws, size_t ws_size,
                              hipStream_t stream) {
    const float* F   = (const float*)d_in[0];
    const float* R   = (const float*)d_in[1];
    const float* Ys  = (const float*)d_in[2];
    const float* Rad = (const float*)d_in[3];
    const float* cg  = (const float*)d_in[4];
    const float* Nn  = (const float*)d_in[5];
    const int*   Ma  = (const int*)d_in[6];
    const int*   Mb  = (const int*)d_in[7];
    float* Out = (float*)d_out;

    const int nE = in_sizes[6];
    hipMemsetAsync(Out, 0, (size_t)out_size * sizeof(float), stream);

    const int grid = (nE + EPB - 1) / EPB;
    hipLaunchKernelGGL(se3_conv, dim3(grid), dim3(BLK), 0, stream,
                       F, R, Ys, Rad, cg, Nn, Ma, Mb, Out, nE);
}